// Round 6
// baseline (144.929 us; speedup 1.0000x reference)
//
#include <hip/hip_runtime.h>

#define B_ 16
#define M_ 200
#define S_ 32
#define C_ 2048
#define V_ 32000
#define D_ 128
#define HOPS_ 3
#define NBLK 256
#define NTHR 1024

#define AG __HIP_MEMORY_SCOPE_AGENT
#define RLX __ATOMIC_RELAXED

// Counter-only grid barrier pieces. Cross-phase data is published with
// agent-scope (write-through) stores, so NO wb/inv fences are needed here:
// __syncthreads() drains vmcnt before the arrive-add.
__device__ __forceinline__ void arrive(unsigned* c) {
    __syncthreads();                      // drains vmcnt for all waves
    if (threadIdx.x == 0) __hip_atomic_fetch_add(c, 1u, RLX, AG);
}
__device__ __forceinline__ void wait_for(unsigned* c, unsigned n) {
    if (threadIdx.x == 0)
        while (__hip_atomic_load(c, RLX, AG) < n) __builtin_amdgcn_s_sleep(1);
    __syncthreads();
}

__global__ void __launch_bounds__(NTHR) k_fused(
        const int* __restrict__ stories, const int* __restrict__ query,
        const int* __restrict__ E, const int* __restrict__ cand,
        const float* __restrict__ embA, const float* __restrict__ embW,
        const float* __restrict__ Hw, const float* __restrict__ Hb,
        float* __restrict__ out, float* __restrict__ m,
        float* __restrict__ u, float* __restrict__ Pt, unsigned* __restrict__ bc) {
    const int t = threadIdx.x;
    const int blk = blockIdx.x;
    const bool isHop = (blk < B_);

    __shared__ float su[D_];
    __shared__ float sattn[M_];
    __shared__ float sred[16 * D_];
    __shared__ float4 su_all[B_][D_ / 4];   // u for all 16 batches (phase 3)
    __shared__ float smx, ssum;

    // Entry acquire: invalidate any stale L2 lines from the previous replay.
    // Off the critical path (once, at start, mostly redundant with dispatch acquire).
    __builtin_amdgcn_fence(__ATOMIC_ACQUIRE, "agent");

    // ---------------- Phase 1: story bags, interleaved across all blocks ----------------
    // wave w of block blk handles sentence bag = blk + 256*w  (64 lanes, float2 each)
    {
        const int lane = t & 63;
        const int wave = t >> 6;
        const int bag = blk + NBLK * wave;          // 0..4095, active < 3200
        if (bag < B_ * M_) {
            const int* idx = stories + bag * S_;
            float2 acc = {0.f, 0.f};
#pragma unroll 8
            for (int s = 0; s < S_; ++s) {
                float2 a = ((const float2*)(embA + (size_t)idx[s] * D_))[lane];
                acc.x += a.x; acc.y += a.y;
            }
            // agent-scope store: write-through to LLC, no dirty L2 line
            __hip_atomic_store(((unsigned long long*)(m + (size_t)bag * D_)) + lane,
                               __builtin_bit_cast(unsigned long long, acc), RLX, AG);
        }
    }
    arrive(bc + 0);

    // ---------------- non-hop blocks: warm L2 while hops run ----------------
    if (!isHop) {
        // embW slice used by this block in phase 3: rows [blk*125, +125)
        const float4* wsrc = (const float4*)(embW + (size_t)blk * 125 * D_);
        for (int i = t; i < 125 * D_ / 4; i += NTHR) {
            float4 w = wsrc[i];
            asm volatile("" :: "v"(w.x));           // keep load alive (no DCE)
        }
        // cand / E slices used by this block in phase 4
        {
            int b = blk >> 4, tile = blk & 15;
            const int4* cs = (const int4*)(cand + tile * 128 * S_);
            for (int i = t; i < 128 * S_ / 4; i += NTHR) {
                int4 x = cs[i]; asm volatile("" :: "v"(x.x));
            }
            const int4* es = (const int4*)(E + ((size_t)b * C_ + tile * 128) * S_);
            for (int i = t; i < 128 * S_ / 4; i += NTHR) {
                int4 x = es[i]; asm volatile("" :: "v"(x.x));
            }
        }
    }
    wait_for(bc + 0, NBLK);

    // ---------------- Phase 2: hops (blocks 0..15), m read normally (L2-fills from LLC) --
    if (isHop) {
        const int b = blk;
        const int lane = t & 63;
        const int wave = t >> 6;
        const float* mb = m + (size_t)b * M_ * D_;
        // u0 computed locally from query (16 KB of embA gathers)
        if (t < D_) {
            float a = 0.f;
#pragma unroll 8
            for (int s = 0; s < S_; ++s) a += embA[(size_t)query[b * S_ + s] * D_ + t];
            su[t] = a;
        }
        __syncthreads();
        for (int hop = 0; hop < HOPS_; ++hop) {
            float2 uu = ((const float2*)su)[lane];
            for (int i = wave; i < M_; i += 16) {
                float2 mv = ((const float2*)(mb + i * D_))[lane];
                float p = mv.x * uu.x + mv.y * uu.y;
#pragma unroll
                for (int o = 32; o; o >>= 1) p += __shfl_xor(p, o);
                if (lane == 0) sattn[i] = p;
            }
            __syncthreads();
            if (wave == 0) {
                float mx = -3.0e38f;
                for (int i = lane; i < M_; i += 64) mx = fmaxf(mx, sattn[i]);
#pragma unroll
                for (int o = 32; o; o >>= 1) mx = fmaxf(mx, __shfl_xor(mx, o));
                float sm = 0.f;
                for (int i = lane; i < M_; i += 64) sm += expf(sattn[i] - mx);
#pragma unroll
                for (int o = 32; o; o >>= 1) sm += __shfl_xor(sm, o);
                if (lane == 0) { smx = mx; ssum = sm; }
            }
            __syncthreads();
            if (t < M_) sattn[t] = expf(sattn[t] - smx) * (1.f / ssum);
            __syncthreads();
            float2 oacc = {0.f, 0.f};
            for (int i = wave; i < M_; i += 16) {
                float a = sattn[i];
                float2 mv = ((const float2*)(mb + i * D_))[lane];
                oacc.x += a * mv.x; oacc.y += a * mv.y;
            }
            ((float2*)sred)[wave * 64 + lane] = oacc;
            __syncthreads();
            int d  = t >> 3;
            int k8 = t & 7;
            float tot = sred[k8 * D_ + d] + sred[(k8 + 8) * D_ + d];
            for (int k = k8; k < D_; k += 8) tot += Hw[d * D_ + k] * su[k];
#pragma unroll
            for (int o = 1; o < 8; o <<= 1) tot += __shfl_xor(tot, o);
            float un = Hb[d] + tot;
            __syncthreads();
            if (k8 == 0) su[d] = un;
            __syncthreads();
        }
        // publish final u[b] via agent-scope stores
        if (t < D_)
            __hip_atomic_store((unsigned*)(u + b * D_ + t),
                               __builtin_bit_cast(unsigned, su[t]), RLX, AG);
        arrive(bc + 16);
    }
    wait_for(bc + 16, B_);

    // ---------------- Phase 3: Pt[b][v] = u[b,:] . embW[v,:]  (125 v per block) --------
    // u read via agent-scope loads (from LLC) into LDS
    {
        unsigned long long vu = __hip_atomic_load(((unsigned long long*)u) + t, RLX, AG);
        ((unsigned long long*)su_all)[t] = vu;      // 1024 * 8 B = 8 KB = all of u
    }
    __syncthreads();
    {
        const int v0 = blk * 125;
#pragma unroll
        for (int it = 0; it < 2; ++it) {
            int item = t + it * NTHR;
            if (item < 125 * B_) {
                int vi = item >> 4;
                int b  = item & 15;
                int v  = v0 + vi;
                const float4* w = (const float4*)(embW + (size_t)v * D_);
                float acc = 0.f;
#pragma unroll 8
                for (int j = 0; j < D_ / 4; ++j) {
                    float4 a = w[j]; float4 x = su_all[b][j];
                    acc += a.x * x.x + a.y * x.y + a.z * x.z + a.w * x.w;
                }
                __hip_atomic_store((unsigned*)(Pt + (size_t)b * V_ + v),
                                   __builtin_bit_cast(unsigned, acc), RLX, AG);
            }
        }
    }
    arrive(bc + 32);
    wait_for(bc + 32, NBLK);

    // ---------------- Phase 4: logits, b-pinned blocks, Pt read normally ----------------
    {
        int b    = blk >> 4;
        int tile = blk & 15;
        int c    = tile * 128 + (t >> 3);
        int q    = t & 7;
        const float* Pb = Pt + (size_t)b * V_;
        const int4* src;
        if (q < 4) src = (const int4*)(cand + c * S_ + q * 8);
        else       src = (const int4*)(E + ((size_t)(b * C_ + c)) * S_ + (q - 4) * 8);
        float acc = 0.f;
#pragma unroll
        for (int j = 0; j < 2; ++j) {
            int4 w = src[j];
            acc += Pb[w.x] + Pb[w.y] + Pb[w.z] + Pb[w.w];
        }
        acc += __shfl_xor(acc, 1);
        acc += __shfl_xor(acc, 2);
        acc += __shfl_xor(acc, 4);
        if (q == 0) out[b * C_ + c] = acc;
    }
}

extern "C" void kernel_launch(void* const* d_in, const int* in_sizes, int n_in,
                              void* d_out, int out_size, void* d_ws, size_t ws_size,
                              hipStream_t stream) {
    const int*   stories = (const int*)d_in[0];
    const int*   query   = (const int*)d_in[1];
    const int*   E       = (const int*)d_in[2];
    const int*   cand    = (const int*)d_in[3];
    const float* embA    = (const float*)d_in[4];
    const float* embW    = (const float*)d_in[5];
    const float* Hw      = (const float*)d_in[6];
    const float* Hb      = (const float*)d_in[7];
    float* out = (float*)d_out;

    char* ws = (char*)d_ws;
    unsigned* bc = (unsigned*)ws;                        // counters at byte 0,64,128
    float* u  = (float*)(ws + 1024);                     // 8 KB
    float* m  = (float*)(ws + 16384);                    // 1.6 MB
    float* Pt = (float*)(ws + 16384 + (size_t)B_ * M_ * D_ * 4);  // 2.0 MB

    (void)hipMemsetAsync(ws, 0, 256, stream);            // zero barrier counters

    void* args[] = { (void*)&stories, (void*)&query, (void*)&E, (void*)&cand,
                     (void*)&embA, (void*)&embW, (void*)&Hw, (void*)&Hb,
                     (void*)&out, (void*)&m, (void*)&u, (void*)&Pt, (void*)&bc };
    (void)hipLaunchCooperativeKernel((const void*)k_fused, dim3(NBLK), dim3(NTHR),
                                     args, 0, stream);
}

// Round 7
// 112.803 us; speedup vs baseline: 1.2848x; 1.2848x over previous
//
#include <hip/hip_runtime.h>

#define B_ 16
#define M_ 200
#define S_ 32
#define C_ 2048
#define V_ 32000
#define D_ 128
#define HOPS_ 3

// ---------------------------------------------------------------------------
// K1: per-batch fused embedding + hops. One block of 1024 threads per batch.
// Story bags are gathered straight into LDS (m[b] = 200x128 f32 = 102.4 KB),
// then 3 hops run entirely from LDS. Only u[b] (128 f32) goes to global.
// ---------------------------------------------------------------------------
__global__ void __launch_bounds__(1024) k_embed_hops(
        const int* __restrict__ stories, const int* __restrict__ query,
        const float* __restrict__ embA, const float* __restrict__ Hw,
        const float* __restrict__ Hb, float* __restrict__ u) {
    const int b = blockIdx.x;
    const int t = threadIdx.x;
    const int lane = t & 63;
    const int wave = t >> 6;                 // 16 waves

    __shared__ float sm[M_][D_];             // 102,400 B
    __shared__ float su[D_];
    __shared__ float sattn[M_];
    __shared__ float sred[16 * D_];          // 8 KB
    __shared__ float smx, ssum;

    // ---- gather bags: wave w handles bags i = w, w+16, ... ; i==200 is the query bag
    for (int g = 0; g < 13; ++g) {
        int i = wave + 16 * g;
        if (i > B_ * 0 + 200) continue;      // i in [0,200]
        const int* idx = (i < 200) ? (stories + (b * M_ + i) * S_)
                                   : (query + b * S_);
        // dual-row float4: lane l covers word s2+(l>>5), cols 4*(l&31)..+3
        float4 acc = {0.f, 0.f, 0.f, 0.f};
#pragma unroll
        for (int s2 = 0; s2 < S_; s2 += 2) {
            int w = idx[s2 + (lane >> 5)];
            const float4* row = (const float4*)(embA + (size_t)w * D_);
            float4 a = row[lane & 31];
            acc.x += a.x; acc.y += a.y; acc.z += a.z; acc.w += a.w;
        }
        // combine the two half-wave partial sums (even words + odd words)
        acc.x += __shfl_xor(acc.x, 32);
        acc.y += __shfl_xor(acc.y, 32);
        acc.z += __shfl_xor(acc.z, 32);
        acc.w += __shfl_xor(acc.w, 32);
        if (lane < 32) {
            if (i < 200) ((float4*)sm[i])[lane] = acc;
            else         ((float4*)su)[lane] = acc;
        }
    }
    __syncthreads();

    // ---- 3 hops, all m-reads from LDS
    for (int hop = 0; hop < HOPS_; ++hop) {
        // scores: attn[i] = sm[i,:] . su   (one row per wave, 64-lane shfl reduce)
        float2 uu = ((const float2*)su)[lane];
        for (int i = wave; i < M_; i += 16) {
            float2 mv = ((const float2*)sm[i])[lane];
            float p = mv.x * uu.x + mv.y * uu.y;
#pragma unroll
            for (int o = 32; o; o >>= 1) p += __shfl_xor(p, o);
            if (lane == 0) sattn[i] = p;
        }
        __syncthreads();
        // softmax max/sum by wave 0
        if (wave == 0) {
            float mx = -3.0e38f;
            for (int i = lane; i < M_; i += 64) mx = fmaxf(mx, sattn[i]);
#pragma unroll
            for (int o = 32; o; o >>= 1) mx = fmaxf(mx, __shfl_xor(mx, o));
            float sm_ = 0.f;
            for (int i = lane; i < M_; i += 64) sm_ += expf(sattn[i] - mx);
#pragma unroll
            for (int o = 32; o; o >>= 1) sm_ += __shfl_xor(sm_, o);
            if (lane == 0) { smx = mx; ssum = sm_; }
        }
        __syncthreads();
        if (t < M_) sattn[t] = expf(sattn[t] - smx) * (1.f / ssum);
        __syncthreads();
        // o[d] = sum_i attn[i]*sm[i][d]  (per-wave partials in sred)
        float2 oacc = {0.f, 0.f};
        for (int i = wave; i < M_; i += 16) {
            float a = sattn[i];
            float2 mv = ((const float2*)sm[i])[lane];
            oacc.x += a * mv.x; oacc.y += a * mv.y;
        }
        ((float2*)sred)[wave * 64 + lane] = oacc;
        __syncthreads();
        // u_new[d] = Hb[d] + o[d] + sum_k Hw[d,k]*su[k]   (8 lanes per d)
        int d  = t >> 3;
        int k8 = t & 7;
        float tot = sred[k8 * D_ + d] + sred[(k8 + 8) * D_ + d];
        for (int k = k8; k < D_; k += 8) tot += Hw[d * D_ + k] * su[k];
#pragma unroll
        for (int o = 1; o < 8; o <<= 1) tot += __shfl_xor(tot, o);
        float un = Hb[d] + tot;
        __syncthreads();
        if (k8 == 0) su[d] = un;
        __syncthreads();
    }
    if (t < D_) u[b * D_ + t] = su[t];
}

// ---------------------------------------------------------------------------
// K2: P[v,b] = dot(u[b,:], embed_W[v,:])   (verbatim from verified R2 kernel)
// ---------------------------------------------------------------------------
__global__ void k_pv(const float* __restrict__ u, const float* __restrict__ embW,
                     float* __restrict__ P) {
    int g = blockIdx.x * 256 + threadIdx.x;   // g = v*16 + b
    int b = g & (B_ - 1);
    int v = g >> 4;
    const float4* w  = (const float4*)(embW + (size_t)v * D_);
    const float4* uu = (const float4*)(u + b * D_);
    float acc = 0.f;
#pragma unroll 8
    for (int j = 0; j < D_ / 4; ++j) {
        float4 a = w[j]; float4 x = uu[j];
        acc += a.x * x.x + a.y * x.y + a.z * x.z + a.w * x.w;
    }
    P[v * B_ + b] = acc;
}

// ---------------------------------------------------------------------------
// K3: logits[b,c] = sum_s P[cand[c,s],b] + sum_s P[E[b,c,s],b]
// (verbatim from verified R2 kernel: 4 lanes per (b,c), shfl combine)
// ---------------------------------------------------------------------------
__global__ void k_logits(const int* __restrict__ cand, const int* __restrict__ E,
                         const float* __restrict__ P, float* __restrict__ out) {
    int g4 = blockIdx.x * 256 + threadIdx.x;  // (b*C + c)*4 + q
    int q = g4 & 3;
    int g = g4 >> 2;
    int c = g & (C_ - 1);
    int b = g >> 11;
    const int4* cs = (const int4*)(cand + c * S_ + q * 8);
    const int4* es = (const int4*)(E + (size_t)g * S_ + q * 8);
    float acc = 0.f;
#pragma unroll
    for (int j = 0; j < 2; ++j) {
        int4 wv = cs[j];
        acc += P[wv.x * B_ + b] + P[wv.y * B_ + b] + P[wv.z * B_ + b] + P[wv.w * B_ + b];
        int4 ev = es[j];
        acc += P[ev.x * B_ + b] + P[ev.y * B_ + b] + P[ev.z * B_ + b] + P[ev.w * B_ + b];
    }
    acc += __shfl_xor(acc, 1);
    acc += __shfl_xor(acc, 2);
    if (q == 0) out[g] = acc;
}

extern "C" void kernel_launch(void* const* d_in, const int* in_sizes, int n_in,
                              void* d_out, int out_size, void* d_ws, size_t ws_size,
                              hipStream_t stream) {
    const int*   stories = (const int*)d_in[0];
    const int*   query   = (const int*)d_in[1];
    const int*   E       = (const int*)d_in[2];
    const int*   cand    = (const int*)d_in[3];
    const float* embA    = (const float*)d_in[4];
    const float* embW    = (const float*)d_in[5];
    const float* Hw      = (const float*)d_in[6];
    const float* Hb      = (const float*)d_in[7];
    float* out = (float*)d_out;

    char* ws = (char*)d_ws;
    float* u = (float*)ws;                 // B*D f32 = 8 KB
    float* P = (float*)(ws + 8192);        // V*B f32 = 2.0 MB

    hipLaunchKernelGGL(k_embed_hops, dim3(B_), dim3(1024), 0, stream,
                       stories, query, embA, Hw, Hb, u);
    hipLaunchKernelGGL(k_pv,     dim3((B_ * V_) / 256), dim3(256), 0, stream, u, embW, P);
    hipLaunchKernelGGL(k_logits, dim3((B_ * C_ * 4) / 256), dim3(256), 0, stream,
                       cand, E, P, out);
}